// Round 4
// baseline (4916.165 us; speedup 1.0000x reference)
//
#include <hip/hip_runtime.h>
#include <stdint.h>

// B=32, L=256, D=128. Reader LSTM scan + attention-memory writer scan.
// ALL inputs/outputs FP32. Round-4: kill the per-step L2->L1 weight
// re-stream (the round-3 bottleneck: 512-640 KB/step, 7.4us/step).
//  - XW = x@Wr+br precomputed full-chip -> bf16 ws (reader streams 1KB/step)
//  - Ur column in 128 VGPRs per thread (reader fetch ~0)
//  - Writer: Uw bf16-packed in 64 VGPRs; Ww/Wc streamed as bf16 (192KB/step
//    vs 640KB fp32). mem register-resident dual-layout as in round 3.

#define LL 256
#define NT 512

typedef float v2f __attribute__((ext_vector_type(2)));

__device__ __forceinline__ float asf(uint32_t u) { union { uint32_t i; float f; } v; v.i = u; return v.f; }
__device__ __forceinline__ float lo2(uint32_t u) { return asf(u << 16); }
__device__ __forceinline__ float hi2(uint32_t u) { return asf(u & 0xffff0000u); }
__device__ __forceinline__ v2f bf2(uint32_t u) { v2f r; r.x = lo2(u); r.y = hi2(u); return r; }
__device__ __forceinline__ float bfu(unsigned short u) { return asf(((uint32_t)u) << 16); }
__device__ __forceinline__ uint32_t bfr(float x) {           // fp32 -> bf16 bits, RTNE
  union { float f; uint32_t i; } v; v.f = x;
  return (v.i + 0x7fffu + ((v.i >> 16) & 1u)) >> 16;
}
__device__ __forceinline__ uint32_t pack2(float a, float b) { return bfr(a) | (bfr(b) << 16); }
__device__ __forceinline__ float hsig(float x) { return fminf(fmaxf(fmaf(x, 0.2f, 0.5f), 0.f), 1.f); }
__device__ __forceinline__ float tanh_fast(float x) {
  x = fminf(fmaxf(x, -15.f), 15.f);
  float e = __expf(2.f * x);
  return (e - 1.f) / (e + 1.f);
}

// ---- Prep 1: XWb[(b*L+t)*512 + j] = bf16(x[b,t,:]@Wr + br) ---------------
__global__ __launch_bounds__(512) void xw_kernel(const float* __restrict__ x,
                                                 const float* __restrict__ Wr,
                                                 const float* __restrict__ br,
                                                 unsigned short* __restrict__ XWb) {
  __shared__ float xr[1024];
  const int tid = threadIdx.x;
  const size_t r0 = (size_t)blockIdx.x * 8;      // 8 (b,t) rows per block
  const float* xg = x + r0 * 128;
  xr[tid] = xg[tid];
  xr[tid + 512] = xg[tid + 512];
  __syncthreads();
  float acc[8];
  const float b0 = br[tid];
#pragma unroll
  for (int r = 0; r < 8; r++) acc[r] = b0;
  for (int k = 0; k < 128; k++) {
    float w = Wr[k * 512 + tid];
#pragma unroll
    for (int r = 0; r < 8; r++) acc[r] = fmaf(w, xr[r * 128 + k], acc[r]);
  }
#pragma unroll
  for (int r = 0; r < 8; r++)
    XWb[(r0 + r) * 512 + tid] = (unsigned short)bfr(acc[r]);
}

// ---- Prep 2: pack 128x512 fp32 W -> bf16-pair uint4 stream layout ---------
// out u32 index (i4*512 + j)*4 + c  holds pack2(W[2p][j], W[2p+1][j]), p=i4*4+c
__global__ __launch_bounds__(512) void packW_kernel(const float* __restrict__ W,
                                                    uint32_t* __restrict__ out) {
  int idx = blockIdx.x * 512 + threadIdx.x;      // 32768
  int i4 = idx >> 11;
  int j  = (idx >> 2) & 511;
  int c  = idx & 3;
  int p  = i4 * 4 + c;
  out[idx] = pack2(W[(2 * p) * 512 + j], W[(2 * p + 1) * 512 + j]);
}

// ---- Prep 3: pack 256x128 fp32 Wc -> bf16-pair uint4 layout ---------------
// out u32 index ((kq*8+i4)*128 + j)*4 + c : k0 = kq*64 + 2*(i4*4+c)
__global__ __launch_bounds__(512) void packWc_kernel(const float* __restrict__ Wc,
                                                     uint32_t* __restrict__ out) {
  int idx = blockIdx.x * 512 + threadIdx.x;      // 16384
  int g = idx >> 9;                              // kq*8 + i4, 0..31
  int j = (idx >> 2) & 127;
  int c = idx & 3;
  int kq = g >> 3, i4 = g & 7;
  int k0 = kq * 64 + 2 * (i4 * 4 + c);
  out[idx] = pack2(Wc[k0 * 128 + j], Wc[(k0 + 1) * 128 + j]);
}

// ---- Fused sequential kernel ----------------------------------------------
__global__ __launch_bounds__(512, 2) void fused_kernel(
    const float* __restrict__ x, const float* __restrict__ Ur,
    const uint32_t* __restrict__ WwP, const uint32_t* __restrict__ UwP,
    const uint32_t* __restrict__ WcP, const unsigned short* __restrict__ XWb,
    const float* __restrict__ bw, const float* __restrict__ bc,
    uint32_t* __restrict__ og, float* __restrict__ out) {
  alignas(16) __shared__ float h_s[128];
  alignas(16) __shared__ float osA[128], osB[128];
  alignas(16) __shared__ float sc_s[256], ee_s[256];
  alignas(16) __shared__ float mr_s[128], ct_s[128];
  alignas(16) __shared__ float pp_s[1024];
  __shared__ float rr_s[16];

  const int b = blockIdx.x, tid = threadIdx.x;
  const int lane = tid & 63, wv = tid >> 6;
  const int l = tid >> 1, hf = tid & 1;          // row-major mem role
  const int q = tid >> 6, dp = tid & 63;         // col-major mem role

  const unsigned short* xwb = XWb + (size_t)b * (LL * 512);
  uint32_t* ogb = og + (size_t)b * (LL * 64);
  const float bwj = bw[tid];
  const float bcj = (tid < 128) ? bc[tid] : 0.f;

  // ================= READER (Ur column in 128 VGPRs) =================
  float ur[128];
#pragma unroll
  for (int k = 0; k < 128; k++) ur[k] = Ur[k * 512 + tid];

  float c_r = 0.f;
  if (tid < 128) h_s[tid] = 0.f;
  __syncthreads();
  for (int t = 0; t < LL; t++) {
    float xwv = bfu(xwb[t * 512 + tid]);
    float a0 = 0.f, a1 = 0.f, a2 = 0.f, a3 = 0.f;
#pragma unroll
    for (int k4 = 0; k4 < 32; k4++) {
      float4 h4 = *(const float4*)&h_s[4 * k4];
      a0 = fmaf(ur[4 * k4 + 0], h4.x, a0);
      a1 = fmaf(ur[4 * k4 + 1], h4.y, a1);
      a2 = fmaf(ur[4 * k4 + 2], h4.z, a2);
      a3 = fmaf(ur[4 * k4 + 3], h4.w, a3);
    }
    pp_s[tid] = (a0 + a1) + (a2 + a3) + xwv;
    __syncthreads();
    if (tid < 128) {
      float zi = pp_s[tid], zf = pp_s[128 + tid], zg = pp_s[256 + tid], zo = pp_s[384 + tid];
      float ii = hsig(zi), ff = hsig(zf), gg = tanh_fast(zg), oo = hsig(zo);
      c_r = fmaf(ff, c_r, ii * gg);
      float h = oo * tanh_fast(c_r);
      h_s[tid] = h;
      float hn = __shfl_down(h, 1);
      if (!(tid & 1)) ogb[t * 64 + (tid >> 1)] = pack2(h, hn);
    }
    __syncthreads();
  }

  // ================= WRITER =================
  // mem (== x, untouched by reader) -> registers, dual layout
  const float* xg = x + (size_t)b * (LL * 128);
  v2f Mr[32], Mc[32];
#pragma unroll
  for (int w = 0; w < 32; w++) Mr[w] = *(const v2f*)(xg + l * 128 + hf * 64 + 2 * w);
#pragma unroll
  for (int i = 0; i < 32; i++) Mc[i] = *(const v2f*)(xg + (q * 32 + i) * 128 + 2 * dp);
  // Uw column j in 16 uint4 regs (bf16 pairs)
  uint4 uwr[16];
  const uint4* UwP4 = (const uint4*)UwP;
#pragma unroll
  for (int i4 = 0; i4 < 16; i4++) uwr[i4] = UwP4[i4 * 512 + tid];

  float c_w = 0.f;
  if (tid < 128) h_s[tid] = 0.f;
  if (tid < 64) { v2f o = bf2(ogb[tid]); osA[2 * tid] = o.x; osA[2 * tid + 1] = o.y; }
  __syncthreads();
  { // prologue: sc_s[l] = mem0[l] . o_0
    v2f S = {0.f, 0.f};
#pragma unroll
    for (int w = 0; w < 32; w++) S += Mr[w] * (*(const v2f*)&osA[hf * 64 + 2 * w]);
    float s = S.x + S.y;
    s += __shfl_xor(s, 1);
    if (hf == 0) sc_s[l] = s;
  }
  __syncthreads();

  const uint4* WwP4 = (const uint4*)WwP;
  const uint4* WcP4 = (const uint4*)WcP;

  for (int t = 0; t < LL; t++) {
    // S1: publish o_t / o_{t+1}; softmax max
    if (tid < 64) {
      v2f o = bf2(ogb[t * 64 + tid]);
      osA[2 * tid] = o.x; osA[2 * tid + 1] = o.y;
    } else if (tid < 128 && t + 1 < LL) {
      int u = tid - 64;
      v2f o = bf2(ogb[(t + 1) * 64 + u]);
      osB[2 * u] = o.x; osB[2 * u + 1] = o.y;
    }
    if (tid < 256) {
      float m = sc_s[tid];
#pragma unroll
      for (int off = 32; off > 0; off >>= 1) m = fmaxf(m, __shfl_xor(m, off));
      if (lane == 0) rr_s[wv] = m;
    }
    __syncthreads();
    // S2: exp + sum
    if (tid < 256) {
      float mx = fmaxf(fmaxf(rr_s[0], rr_s[1]), fmaxf(rr_s[2], rr_s[3]));
      float e = __expf(sc_s[tid] - mx);
      ee_s[tid] = e;
      float s2 = e;
#pragma unroll
      for (int off = 32; off > 0; off >>= 1) s2 += __shfl_xor(s2, off);
      if (lane == 0) rr_s[8 + wv] = s2;
    }
    __syncthreads();
    const float inv = 1.f / (rr_s[8] + rr_s[9] + rr_s[10] + rr_s[11]);
    // S3: m_rt partials (col-major regs)
    {
      v2f P = {0.f, 0.f};
#pragma unroll
      for (int i = 0; i < 32; i++) P += Mc[i] * ee_s[q * 32 + i];
      *(v2f*)&pp_s[q * 128 + 2 * dp] = P;
    }
    __syncthreads();
    // S4: m_rt final
    if (tid < 128) {
      float s = 0.f;
#pragma unroll
      for (int g = 0; g < 8; g++) s += pp_s[g * 128 + tid];
      mr_s[tid] = s * inv;
    }
    __syncthreads();
    // S5: c_t partials = [o_t | m_rt] @ Wc (bf16 stream)
    {
      const int j = tid & 127, kq = tid >> 7;
      const float* in = (kq < 2) ? (osA + kq * 64) : (mr_s + (kq - 2) * 64);
      v2f A = {0.f, 0.f};
#pragma unroll
      for (int i4 = 0; i4 < 8; i4++) {
        uint4 wq = WcP4[(kq * 8 + i4) * 128 + j];
        const v2f* vp = (const v2f*)&in[8 * i4];
        A += bf2(wq.x) * vp[0];
        A += bf2(wq.y) * vp[1];
        A += bf2(wq.z) * vp[2];
        A += bf2(wq.w) * vp[3];
      }
      pp_s[kq * 128 + j] = A.x + A.y;
    }
    __syncthreads();
    // S6: c_t final
    if (tid < 128)
      ct_s[tid] = bcj + pp_s[tid] + pp_s[128 + tid] + pp_s[256 + tid] + pp_s[384 + tid];
    __syncthreads();
    // S7: z[j] = ct@Ww (bf16 stream) + h@Uw (regs) + bw
    {
      v2f A = {0.f, 0.f};
#pragma unroll
      for (int i4 = 0; i4 < 16; i4++) {
        uint4 wq = WwP4[i4 * 512 + tid];
        const v2f* cp = (const v2f*)&ct_s[8 * i4];
        A += bf2(wq.x) * cp[0];
        A += bf2(wq.y) * cp[1];
        A += bf2(wq.z) * cp[2];
        A += bf2(wq.w) * cp[3];
      }
#pragma unroll
      for (int i4 = 0; i4 < 16; i4++) {
        uint4 uq = uwr[i4];
        const v2f* hp = (const v2f*)&h_s[8 * i4];
        A += bf2(uq.x) * hp[0];
        A += bf2(uq.y) * hp[1];
        A += bf2(uq.z) * hp[2];
        A += bf2(uq.w) * hp[3];
      }
      pp_s[tid] = A.x + A.y + bwj;
    }
    __syncthreads();
    // S8: gates
    if (tid < 128) {
      float zi = pp_s[tid], zf = pp_s[128 + tid], zg = pp_s[256 + tid], zo = pp_s[384 + tid];
      float ii = hsig(zi), ff = hsig(zf), gg = tanh_fast(zg), oo = hsig(zo);
      c_w = fmaf(ff, c_w, ii * gg);
      float h = oo * tanh_fast(c_w);
      h_s[tid] = h;
    }
    __syncthreads();
    // S9: mem update (both layouts, identical math) + fused next scores
    if (t + 1 < LL) {
      const float zr = ee_s[l] * inv;
      v2f S = {0.f, 0.f};
#pragma unroll
      for (int w = 0; w < 32; w++) {
        v2f h2 = *(const v2f*)&h_s[hf * 64 + 2 * w];
        v2f m = Mr[w];
        v2f n = m + (h2 - m) * zr;
        Mr[w] = n;
        S += n * (*(const v2f*)&osB[hf * 64 + 2 * w]);
      }
      float s = S.x + S.y;
      s += __shfl_xor(s, 1);
      if (hf == 0) sc_s[l] = s;
      v2f hc = *(const v2f*)&h_s[2 * dp];
#pragma unroll
      for (int i = 0; i < 32; i++) {
        float zc = ee_s[q * 32 + i] * inv;
        v2f m = Mc[i];
        Mc[i] = m + (hc - m) * zc;
      }
    }
    __syncthreads();
  }

  if (tid < 128) out[b * 128 + tid] = h_s[tid];
}

extern "C" void kernel_launch(void* const* d_in, const int* in_sizes, int n_in,
                              void* d_out, int out_size, void* d_ws, size_t ws_size,
                              hipStream_t stream) {
  const float* x  = (const float*)d_in[0];
  const float* Wr = (const float*)d_in[1];
  const float* Ur = (const float*)d_in[2];
  const float* br = (const float*)d_in[3];
  const float* Ww = (const float*)d_in[4];
  const float* Uw = (const float*)d_in[5];
  const float* bw = (const float*)d_in[6];
  const float* Wc = (const float*)d_in[7];
  const float* bc = (const float*)d_in[8];
  float* out = (float*)d_out;

  // ws layout (u32 units): og 524288 (2MB) | XWb 2097152 (8MB as ushort) |
  // WwP 32768 | UwP 32768 | WcP 16384  -> 10.81 MB total
  uint32_t* wsw = (uint32_t*)d_ws;
  uint32_t* og = wsw;
  unsigned short* XWb = (unsigned short*)(wsw + 524288);
  uint32_t* WwP = wsw + 524288 + 2097152;
  uint32_t* UwP = WwP + 32768;
  uint32_t* WcP = UwP + 32768;

  xw_kernel<<<32 * LL / 8, 512, 0, stream>>>(x, Wr, br, XWb);
  packW_kernel<<<64, 512, 0, stream>>>(Ww, WwP);
  packW_kernel<<<64, 512, 0, stream>>>(Uw, UwP);
  packWc_kernel<<<32, 512, 0, stream>>>(Wc, WcP);
  fused_kernel<<<32, NT, 0, stream>>>(x, Ur, WwP, UwP, WcP, XWb, bw, bc, og, out);
}